// Round 15
// baseline (668.627 us; speedup 1.0000x reference)
//
#include <hip/hip_runtime.h>
#include <stdint.h>

// MultiAttention fused kernel for MI355X (gfx950) — round 15
// B=131072 rows; D=105 (80 hm + 20 me + 5 tf); 10 attention groups.
// out  [B,105] fp32; alpha [B,1050] fp32 (d_out = [out | alpha]).
//
// R15 = R14 (clean-codegen drain-free B2, 242us ~ R8's 240) + NONTEMPORAL
// stores for alpha and out. Single-variable test: alpha is a 550MB streaming
// output, never re-read; plain stores write-allocate in L2 (3.4MB/XCD/group)
// and evict the weight slabs + ctx that staging then re-fetches from HBM
// (FETCH 30MB > ~16MB compulsory). nt bypasses L2 allocation. R11's nt test
// was confounded by the 64-VGPR spill; R14's builtin-only sync is preserved
// (nt is store metadata, not an inline-asm node).

#define NATT 10
#define DD   105
#define KP   112          // ctx k pitch (0..104 real, 105=1.0 bias, 106..111=0)
#define RPB  128          // rows per block (8 waves x 16)
#define SLAB 12800        // shorts per operand group slab (25600 B = 25 chunks)
#define HOFF 10752        // shorts: offset of half-frag region (21 full KB)
#define FRAG_ELEMS 512    // full frag: 64 lanes x 8 bf16 (1KB)

typedef __attribute__((ext_vector_type(8))) short short8v;
typedef __attribute__((ext_vector_type(4))) short short4v;
typedef __attribute__((ext_vector_type(4))) float f4;
typedef float f4u __attribute__((ext_vector_type(4), aligned(4)));
typedef __attribute__((ext_vector_type(4))) unsigned int u32x4;
typedef __attribute__((ext_vector_type(2))) unsigned int u32x2;

__device__ __forceinline__ short f2bf(float x) {
  unsigned int u = __builtin_bit_cast(unsigned int, x);
  unsigned int r = (u + 0x7FFFu + ((u >> 16) & 1u)) >> 16;   // RNE
  return (short)(r & 0xFFFFu);
}
__device__ __forceinline__ float bf2f(int b) {
  unsigned int u = ((unsigned int)(b & 0xFFFF)) << 16;
  return __builtin_bit_cast(float, u);
}
__device__ __forceinline__ unsigned int pkbf(float lo, float hi) {
  unsigned int r;
  asm("v_cvt_pk_bf16_f32 %0, %1, %2" : "=v"(r) : "v"(lo), "v"(hi));
  return r;
}
__device__ __forceinline__ void gload_lds16(const void* g, void* l) {
  __builtin_amdgcn_global_load_lds(
      (const __attribute__((address_space(1))) unsigned int*)g,
      (__attribute__((address_space(3))) unsigned int*)l, 16, 0, 0);
}
__device__ __forceinline__ void st_nt4(float* p, f4 v) {
  __builtin_nontemporal_store(v, (f4u*)p);
}

// ---------------- prep: build bf16 fragment packs (identical to R8) ----------------
__device__ __forceinline__ float wblockdiag(int jout, int i,
    const float* HMw, const float* MEw, const float* TFw) {
  float v = 0.f;
  if (i < 800)       { if (jout < 80)                v = HMw[jout * 800 + i]; }
  else if (i < 1000) { if (jout >= 80 && jout < 100) v = MEw[(jout - 80) * 200 + (i - 800)]; }
  else               { if (jout >= 100)              v = TFw[(jout - 100) * 50 + (i - 1000)]; }
  return v;
}

__global__ void prep_kernel(const float* __restrict__ Aw, const float* __restrict__ Ab,
                            const float* __restrict__ HMw, const float* __restrict__ HMb,
                            const float* __restrict__ MEw, const float* __restrict__ MEb,
                            const float* __restrict__ TFw, const float* __restrict__ TFb,
                            short* __restrict__ Afrag, short* __restrict__ Wfrag,
                            unsigned char* __restrict__ Lut8)
{
  const float L2E = 1.4426950408889634f;
  int tid = blockIdx.x * blockDim.x + threadIdx.x;
  int NT  = gridDim.x * blockDim.x;

  // A full frags: (c<3,T): n=T*16+(l&15), k=c*32+(l>>4)*8+j (<=95)
  for (int a = tid; a < NATT * 21 * 512; a += NT) {
    int j = a & 7, l = (a >> 3) & 63;
    int fi = (a >> 9) % 21, g = (a >> 9) / 21;
    int c = fi / 7, T = fi % 7;
    int n = T * 16 + (l & 15);
    int k = c * 32 + (l >> 4) * 8 + j;
    float v = (n < DD) ? Aw[(g * DD + n) * DD + k] * L2E : 0.f;
    Afrag[g * SLAB + fi * 512 + l * 8 + j] = f2bf(v);
  }
  // A half frags: slot j<4 <-> kk=96+(l>>4)*4+j
  for (int a = tid; a < NATT * 7 * 256; a += NT) {
    int j = a & 3, l = (a >> 2) & 63;
    int T = (a >> 8) % 7, g = (a >> 8) / 7;
    int n = T * 16 + (l & 15);
    int kk = 96 + (l >> 4) * 4 + j;
    float v;
    if (kk < DD)       v = (n < DD) ? Aw[(g * DD + n) * DD + kk] * L2E : 0.f;
    else if (kk == DD) v = (n < DD) ? Ab[g * DD + n] * L2E : -1e30f;
    else               v = 0.f;
    Afrag[g * SLAB + HOFF + T * 256 + l * 4 + j] = f2bf(v);
  }
  for (int a = tid; a < NATT * 256; a += NT)
    Afrag[(a >> 8) * SLAB + 12544 + (a & 255)] = 0;

  // W full frags: kappa2 map il = cc*32+gg*4+(j&3)+16*(j>>2)
  for (int a = tid; a < NATT * 21 * 512; a += NT) {
    int j = a & 7, l = (a >> 3) & 63;
    int fi = (a >> 9) % 21, g = (a >> 9) / 21;
    int cc = fi / 7, jt = fi % 7;
    int jout = jt * 16 + (l & 15);
    int gg = l >> 4;
    int il = cc * 32 + gg * 4 + (j & 3) + ((j >> 2) << 4);
    float v = (jout < DD) ? wblockdiag(jout, g * DD + il, HMw, MEw, TFw) : 0.f;
    Wfrag[g * SLAB + fi * 512 + l * 8 + j] = f2bf(v);
  }
  // W half frags: il=96+gg*4+j (j<4); il==105&&g==0 -> out-bias
  for (int a = tid; a < NATT * 7 * 256; a += NT) {
    int j = a & 3, l = (a >> 2) & 63;
    int jt = (a >> 8) % 7, g = (a >> 8) / 7;
    int jout = jt * 16 + (l & 15);
    int gg = l >> 4;
    int il = 96 + gg * 4 + j;
    float v = 0.f;
    if (il < DD && jout < DD) v = wblockdiag(jout, g * DD + il, HMw, MEw, TFw);
    else if (il == DD && g == 0 && jout < DD) {
      if (jout < 80)       v = HMb[jout];
      else if (jout < 100) v = MEb[jout - 80];
      else                 v = TFb[jout - 100];
    }
    Wfrag[g * SLAB + HOFF + jt * 256 + l * 4 + j] = f2bf(v);
  }
  for (int a = tid; a < NATT * 256; a += NT)
    Wfrag[(a >> 8) * SLAB + 12544 + (a & 255)] = 0;

  for (int a = tid; a < NATT * KP; a += NT) {
    int g = a / KP, n = a - g * KP;
    int i = g * DD + n;
    int col;
    if (i < 800)       col = i % 80;
    else if (i < 1000) col = 80 + (i - 800) % 20;
    else if (i < 1050) col = 100 + (i - 1000) % 5;
    else               col = 100;  // alpha==0 there
    Lut8[a] = (unsigned char)col;
  }
}

// ---------------- main fused kernel ----------------
// 1024 blocks x 512 threads; 8 waves x 16 rows; B1=__syncthreads (full drain,
// guards W), B2=builtin vmcnt(8)+lgkm(0)+s_barrier (A landed; 8 alpha stores
// keep flying). LDS: 28672+25600+25600+1120 = 80992B -> 2 blocks/CU.
__global__ __launch_bounds__(512, 4)
void fused_main(const float* __restrict__ hm, const float* __restrict__ me,
                const float* __restrict__ tf,
                const short* __restrict__ Afrag, const short* __restrict__ Wfrag,
                const unsigned char* __restrict__ Lut8,
                float* __restrict__ out, float* __restrict__ alphaOut)
{
  __shared__ __align__(16) short sCtx[RPB * KP];        // 28672 B
  __shared__ __align__(16) short sAb[SLAB];             // 25600 B
  __shared__ __align__(16) short sWb[SLAB];             // 25600 B
  __shared__ __align__(4)  unsigned char sLut8[NATT * KP]; // 1120 B

  const int tid  = threadIdx.x;
  const int lane = tid & 63;
  const int wave = tid >> 6;          // 0..7
  const int l15  = lane & 15;
  const int g16  = lane >> 4;
  const long rowbase = (long)blockIdx.x * RPB;
  const int wrow0 = wave * 16;

  // ---- issue A(0), W(0) staging (25 chunks each, over 8 waves) ----
  #pragma unroll
  for (int q = 0; q < 4; ++q) {
    int ch = q * 8 + wave;
    if (ch < 25) {
      gload_lds16(Afrag + ch * 512 + lane * 8, sAb + ch * 512 + lane * 8);
      gload_lds16(Wfrag + ch * 512 + lane * 8, sWb + ch * 512 + lane * 8);
    }
  }

  // ---- wave-private ctx staging (rows wrow0..wrow0+15), KP=112 ----
  for (int q = lane; q < 16 * 20; q += 64) {        // hm: 20 f4 per row
    int r = q / 20, c = q - r * 20;
    f4 v = *(const f4*)(hm + (rowbase + wrow0 + r) * 80 + c * 4);
    u32x2 b; b[0] = pkbf(v[0], v[1]); b[1] = pkbf(v[2], v[3]);
    *(u32x2*)&sCtx[(wrow0 + r) * KP + c * 4] = b;
  }
  for (int q = lane; q < 16 * 5; q += 64) {         // me: 5 f4 per row
    int r = q / 5, c = q - r * 5;
    f4 v = *(const f4*)(me + (rowbase + wrow0 + r) * 20 + c * 4);
    u32x2 b; b[0] = pkbf(v[0], v[1]); b[1] = pkbf(v[2], v[3]);
    *(u32x2*)&sCtx[(wrow0 + r) * KP + 80 + c * 4] = b;
  }
  for (int q = lane; q < 16 * 5; q += 64) {         // tf: 5 scalars per row
    int r = q / 5, c = q - r * 5;
    sCtx[(wrow0 + r) * KP + 100 + c] = f2bf(tf[(rowbase + wrow0 + r) * 5 + c]);
  }
  for (int q = lane; q < 16 * 7; q += 64) {         // cols 105..111; col105 = 1.0
    int r = q / 7, c = q - r * 7;
    sCtx[(wrow0 + r) * KP + 105 + c] = (c == 0) ? (short)0x3F80 : (short)0;
  }
  for (int q = tid; q < (NATT * KP) / 4; q += 512)  // u8 LUT
    ((unsigned int*)sLut8)[q] = ((const unsigned int*)Lut8)[q];

  // ---- preload ctx MFMA fragments (group-invariant, wave-private rows) ----
  short8v cf[3];
  #pragma unroll
  for (int c = 0; c < 3; ++c)
    cf[c] = *(const short8v*)&sCtx[(wrow0 + l15) * KP + c * 32 + g16 * 8];
  short8v cf3x;
  {
    short4v c4 = *(const short4v*)&sCtx[(wrow0 + l15) * KP + 96 + g16 * 4];
    cf3x = short8v{c4[0], c4[1], c4[2], c4[3], 0, 0, 0, 0};
  }

  f4 acc2[7];
  #pragma unroll
  for (int jt = 0; jt < 7; ++jt) {
    acc2[jt][0]=0.f; acc2[jt][1]=0.f; acc2[jt][2]=0.f; acc2[jt][3]=0.f;
  }

  __syncthreads();   // prologue: full drain (A0/W0 landed, ctx/LUT visible)

  for (int g = 0; g < NATT; ++g) {
    // ---- GEMM1: z tile D[n][r], n=16T+4*g16+reg, r=l15; K=112 ----
    f4 za[7];
    #pragma unroll
    for (int T = 0; T < 7; ++T) { za[T][0]=0.f; za[T][1]=0.f; za[T][2]=0.f; za[T][3]=0.f; }

    #pragma unroll
    for (int c = 0; c < 3; ++c) {
      #pragma unroll
      for (int T = 0; T < 7; ++T) {
        short8v af = *(const short8v*)&sAb[(c * 7 + T) * FRAG_ELEMS + lane * 8];
        za[T] = __builtin_amdgcn_mfma_f32_16x16x32_bf16(af, cf[c], za[T], 0, 0, 0);
      }
    }
    #pragma unroll
    for (int T = 0; T < 7; ++T) {                     // half chunk k=96..111
      short4v a4 = *(const short4v*)&sAb[HOFF + T * 256 + lane * 4];
      short8v af3 = short8v{a4[0], a4[1], a4[2], a4[3], 0, 0, 0, 0};
      za[T] = __builtin_amdgcn_mfma_f32_16x16x32_bf16(af3, cf3x, za[T], 0, 0, 0);
    }

    // ---- B1: full drain barrier (as R8). Guarantees W(g) landed; also
    //      retires stores(g-1), which by now had GEMM2+GEMM1 to drain. ----
    __syncthreads();

    // ---- stage A(g+1): 3-4 chunks per wave, guarded by B2's vmcnt(8) ----
    if (g < NATT - 1) {
      const short* src = Afrag + (g + 1) * SLAB;
      #pragma unroll
      for (int q = 0; q < 4; ++q) {
        int ch = q * 8 + wave;
        if (ch < 25) gload_lds16(src + ch * 512 + lane * 8, sAb + ch * 512 + lane * 8);
      }
    }

    // ---- LUT quads ----
    unsigned int cq[7];
    #pragma unroll
    for (int T = 0; T < 7; ++T)
      cq[T] = *(const unsigned int*)&sLut8[g * KP + T * 16 + g16 * 4];

    // ---- softmax (exp2 of prescaled z, no max-subtract) ----
    float s = 0.f;
    #pragma unroll
    for (int T = 0; T < 7; ++T)
      #pragma unroll
      for (int k = 0; k < 4; ++k) {
        float p = exp2f(za[T][k]);
        za[T][k] = p;
        s += p;
      }
    s += __shfl_xor(s, 16);
    s += __shfl_xor(s, 32);
    float inv = __fdividef(1.f, s);

    const int rowl = wrow0 + l15;
    float* arow = alphaOut + (rowbase + rowl) * 1050 + g * DD;
    const short* crow = &sCtx[rowl * KP];

    // ---- alpha store (nontemporal, exactly 8 store instrs/wave) + h build ----
    u32x4 hfu[4];
    #pragma unroll
    for (int T = 0; T < 7; ++T) {
      f4 av = za[T] * inv;
      int n0 = T * 16 + g16 * 4;
      if (T < 6) {
        st_nt4(arow + n0, av);
      } else {
        if (g16 < 2)       st_nt4(arow + n0, av);
        else if (g16 == 2) __builtin_nontemporal_store(av[0], arow + 104);
      }
      float h0 = av[0] * bf2f(crow[(cq[T] >>  0) & 0xFF]);
      float h1 = av[1] * bf2f(crow[(cq[T] >>  8) & 0xFF]);
      float h2 = av[2] * bf2f(crow[(cq[T] >> 16) & 0xFF]);
      float h3 = av[3] * bf2f(crow[(cq[T] >> 24) & 0xFF]);
      hfu[T >> 1][(T & 1) * 2 + 0] = pkbf(h0, h1);
      hfu[T >> 1][(T & 1) * 2 + 1] = pkbf(h2, h3);
    }
    hfu[3][2] = 0u; hfu[3][3] = 0u;                 // half-chunk upper slots = 0
    if (g == 0 && g16 == 2) {                       // il=105 slot := 1.0 (out-bias)
      hfu[3][0] = (hfu[3][0] & 0xFFFFu) | 0x3F800000u;
    }

    // ---- GEMM2 from LDS: jt-outer; 3 full + 1 half chunk per jt ----
    short8v ha0 = __builtin_bit_cast(short8v, hfu[0]);
    short8v ha1 = __builtin_bit_cast(short8v, hfu[1]);
    short8v ha2 = __builtin_bit_cast(short8v, hfu[2]);
    short8v ha3 = __builtin_bit_cast(short8v, hfu[3]);
    #pragma unroll
    for (int jt = 0; jt < 7; ++jt) {
      short8v w0 = *(const short8v*)&sWb[(0 * 7 + jt) * FRAG_ELEMS + lane * 8];
      short8v w1 = *(const short8v*)&sWb[(1 * 7 + jt) * FRAG_ELEMS + lane * 8];
      short8v w2 = *(const short8v*)&sWb[(2 * 7 + jt) * FRAG_ELEMS + lane * 8];
      short4v w3h = *(const short4v*)&sWb[HOFF + jt * 256 + lane * 4];
      short8v w3 = short8v{w3h[0], w3h[1], w3h[2], w3h[3], 0, 0, 0, 0};
      f4 a = acc2[jt];
      a = __builtin_amdgcn_mfma_f32_16x16x32_bf16(ha0, w0, a, 0, 0, 0);
      a = __builtin_amdgcn_mfma_f32_16x16x32_bf16(ha1, w1, a, 0, 0, 0);
      a = __builtin_amdgcn_mfma_f32_16x16x32_bf16(ha2, w2, a, 0, 0, 0);
      a = __builtin_amdgcn_mfma_f32_16x16x32_bf16(ha3, w3, a, 0, 0, 0);
      acc2[jt] = a;
    }

    // ---- B2 (drain-free): vmcnt(8) [A(g+1) landed; 8 alpha stores younger,
    //      keep flying] + lgkmcnt(0) [sWb reads retired], then raw barrier.
    //      Builtins only (R11-R13: INLINEASM sync nodes -> 64-VGPR spill).
    __builtin_amdgcn_s_waitcnt(0x0078);   // vmcnt=8 | expcnt=7<<4 | lgkm=0<<8
    __builtin_amdgcn_s_barrier();

    // ---- stage W(g+1) (guarded by next B1's full drain) ----
    if (g < NATT - 1) {
      const short* src = Wfrag + (g + 1) * SLAB;
      #pragma unroll
      for (int q = 0; q < 4; ++q) {
        int ch = q * 8 + wave;
        if (ch < 25) gload_lds16(src + ch * 512 + lane * 8, sWb + ch * 512 + lane * 8);
      }
    }
  }

  // ---- epilogue: bias already in acc2; D2[r][j]: r=4*g16+k, j=16*jt+l15 ----
  #pragma unroll
  for (int jt = 0; jt < 7; ++jt) {
    int j = jt * 16 + l15;
    if (j < DD) {
      #pragma unroll
      for (int k = 0; k < 4; ++k) {
        long row = rowbase + wrow0 + g16 * 4 + k;
        __builtin_nontemporal_store(acc2[jt][k], out + row * DD + j);
      }
    }
  }
}

// ---------------- launch ----------------
extern "C" void kernel_launch(void* const* d_in, const int* in_sizes, int n_in,
                              void* d_out, int out_size, void* d_ws, size_t ws_size,
                              hipStream_t stream)
{
  const float* hm  = (const float*)d_in[0];
  const float* me  = (const float*)d_in[1];
  const float* tf  = (const float*)d_in[2];
  const float* Aw  = (const float*)d_in[3];
  const float* Ab  = (const float*)d_in[4];
  const float* HMw = (const float*)d_in[5];
  const float* HMb = (const float*)d_in[6];
  const float* MEw = (const float*)d_in[7];
  const float* MEb = (const float*)d_in[8];
  const float* TFw = (const float*)d_in[9];
  const float* TFb = (const float*)d_in[10];

  char* ws = (char*)d_ws;
  short* Afrag = (short*)(ws + 0);                 // 256000 B
  short* Wfrag = (short*)(ws + 256000);            // 256000 B
  unsigned char* Lut8 = (unsigned char*)(ws + 512000); // 1120 B (total 513120)

  float* outP     = (float*)d_out;
  float* alphaOut = outP + (long)131072 * DD;

  prep_kernel<<<320, 256, 0, stream>>>(Aw, Ab, HMw, HMb, MEw, MEb, TFw, TFb,
                                       Afrag, Wfrag, Lut8);
  fused_main<<<1024, 512, 0, stream>>>(hm, me, tf, Afrag, Wfrag, Lut8,
                                       outP, alphaOut);
}

// Round 16
// 239.258 us; speedup vs baseline: 2.7946x; 2.7946x over previous
//
#include <hip/hip_runtime.h>
#include <stdint.h>

// MultiAttention fused kernel for MI355X (gfx950) — round 16 (FINAL: R8 revert)
// B=131072 rows; D=105 (80 hm + 20 me + 5 tf); 10 attention groups.
// out  [B,105] fp32; alpha [B,1050] fp32 (d_out = [out | alpha]).
//
// R16 = exact R8, the best clean-codegen kernel (239.7us measured).
// Session summary of what's in here and why:
//  - Both GEMMs via mfma_f32_16x16x32_bf16; weights pre-packed in exact
//    wave-fragment order (prep_kernel) so operand loads are contiguous.
//  - A and W fragment slabs staged in block-shared LDS via global_load_lds
//    (async, zero VGPR), single-buffered, prefetched one group ahead under
//    softmax+GEMM2 / GEMM1 respectively; 2 __syncthreads per group whose
//    implicit vmcnt(0) drain is the staging fence.
//  - K trimmed 128->112 (half-fragment 4th chunk on both operands) to fit
//    ctx(28672)+A(25600)+W(25600)+lut(1120)=80992B LDS -> 2 blocks/CU,
//    16 waves/CU at the 128-VGPR cap (512 threads, launch_bounds(512,4)).
//  - Softmax: A prescaled by log2(e) in prep -> raw v_exp_f32, no
//    max-subtract (z bounded ~4; pad cols get -1e30 bias -> exp=0).
//  - A_b folded via ctx col105==1.0; out-bias folded via il=105 slot at g==0.
//  - alpha stored as dwordx4 (8 store instrs/wave/group); h built from LDS
//    ctx gathers through a u8 column LUT; pkbf (v_cvt_pk_bf16_f32) packing.
// Toolchain landmine (R11/R12/R13/R15): inline-asm s_waitcnt/s_barrier,
// amdgpu_waves_per_eu, and __builtin_nontemporal_store each flip the
// allocator to 8 waves/EU -> 64 VGPR -> ~500MB scratch spill -> 2.7x slower.
// This version uses ONLY plain __syncthreads + standard stores.

#define NATT 10
#define DD   105
#define KP   112          // ctx k pitch (0..104 real, 105=1.0 bias, 106..111=0)
#define RPB  128          // rows per block (8 waves x 16)
#define SLAB 12800        // shorts per operand group slab (25600 B = 25 chunks)
#define HOFF 10752        // shorts: offset of half-frag region (21 full KB)
#define FRAG_ELEMS 512    // full frag: 64 lanes x 8 bf16 (1KB)

typedef __attribute__((ext_vector_type(8))) short short8v;
typedef __attribute__((ext_vector_type(4))) short short4v;
typedef __attribute__((ext_vector_type(4))) float f4;
typedef float f4u __attribute__((ext_vector_type(4), aligned(4)));
typedef __attribute__((ext_vector_type(4))) unsigned int u32x4;
typedef __attribute__((ext_vector_type(2))) unsigned int u32x2;

__device__ __forceinline__ short f2bf(float x) {
  unsigned int u = __builtin_bit_cast(unsigned int, x);
  unsigned int r = (u + 0x7FFFu + ((u >> 16) & 1u)) >> 16;   // RNE
  return (short)(r & 0xFFFFu);
}
__device__ __forceinline__ float bf2f(int b) {
  unsigned int u = ((unsigned int)(b & 0xFFFF)) << 16;
  return __builtin_bit_cast(float, u);
}
__device__ __forceinline__ unsigned int pkbf(float lo, float hi) {
  unsigned int r;
  asm("v_cvt_pk_bf16_f32 %0, %1, %2" : "=v"(r) : "v"(lo), "v"(hi));
  return r;
}
__device__ __forceinline__ void gload_lds16(const void* g, void* l) {
  __builtin_amdgcn_global_load_lds(
      (const __attribute__((address_space(1))) unsigned int*)g,
      (__attribute__((address_space(3))) unsigned int*)l, 16, 0, 0);
}

// ---------------- prep: build bf16 fragment packs ----------------
__device__ __forceinline__ float wblockdiag(int jout, int i,
    const float* HMw, const float* MEw, const float* TFw) {
  float v = 0.f;
  if (i < 800)       { if (jout < 80)                v = HMw[jout * 800 + i]; }
  else if (i < 1000) { if (jout >= 80 && jout < 100) v = MEw[(jout - 80) * 200 + (i - 800)]; }
  else               { if (jout >= 100)              v = TFw[(jout - 100) * 50 + (i - 1000)]; }
  return v;
}

__global__ void prep_kernel(const float* __restrict__ Aw, const float* __restrict__ Ab,
                            const float* __restrict__ HMw, const float* __restrict__ HMb,
                            const float* __restrict__ MEw, const float* __restrict__ MEb,
                            const float* __restrict__ TFw, const float* __restrict__ TFb,
                            short* __restrict__ Afrag, short* __restrict__ Wfrag,
                            unsigned char* __restrict__ Lut8)
{
  const float L2E = 1.4426950408889634f;
  int tid = blockIdx.x * blockDim.x + threadIdx.x;
  int NT  = gridDim.x * blockDim.x;

  // A full frags: (c<3,T): n=T*16+(l&15), k=c*32+(l>>4)*8+j (<=95)
  for (int a = tid; a < NATT * 21 * 512; a += NT) {
    int j = a & 7, l = (a >> 3) & 63;
    int fi = (a >> 9) % 21, g = (a >> 9) / 21;
    int c = fi / 7, T = fi % 7;
    int n = T * 16 + (l & 15);
    int k = c * 32 + (l >> 4) * 8 + j;
    float v = (n < DD) ? Aw[(g * DD + n) * DD + k] * L2E : 0.f;
    Afrag[g * SLAB + fi * 512 + l * 8 + j] = f2bf(v);
  }
  // A half frags: slot j<4 <-> kk=96+(l>>4)*4+j
  for (int a = tid; a < NATT * 7 * 256; a += NT) {
    int j = a & 3, l = (a >> 2) & 63;
    int T = (a >> 8) % 7, g = (a >> 8) / 7;
    int n = T * 16 + (l & 15);
    int kk = 96 + (l >> 4) * 4 + j;
    float v;
    if (kk < DD)       v = (n < DD) ? Aw[(g * DD + n) * DD + kk] * L2E : 0.f;
    else if (kk == DD) v = (n < DD) ? Ab[g * DD + n] * L2E : -1e30f;
    else               v = 0.f;
    Afrag[g * SLAB + HOFF + T * 256 + l * 4 + j] = f2bf(v);
  }
  for (int a = tid; a < NATT * 256; a += NT)
    Afrag[(a >> 8) * SLAB + 12544 + (a & 255)] = 0;

  // W full frags: kappa2 map il = cc*32+gg*4+(j&3)+16*(j>>2)
  for (int a = tid; a < NATT * 21 * 512; a += NT) {
    int j = a & 7, l = (a >> 3) & 63;
    int fi = (a >> 9) % 21, g = (a >> 9) / 21;
    int cc = fi / 7, jt = fi % 7;
    int jout = jt * 16 + (l & 15);
    int gg = l >> 4;
    int il = cc * 32 + gg * 4 + (j & 3) + ((j >> 2) << 4);
    float v = (jout < DD) ? wblockdiag(jout, g * DD + il, HMw, MEw, TFw) : 0.f;
    Wfrag[g * SLAB + fi * 512 + l * 8 + j] = f2bf(v);
  }
  // W half frags: il=96+gg*4+j (j<4); il==105&&g==0 -> out-bias
  for (int a = tid; a < NATT * 7 * 256; a += NT) {
    int j = a & 3, l = (a >> 2) & 63;
    int jt = (a >> 8) % 7, g = (a >> 8) / 7;
    int jout = jt * 16 + (l & 15);
    int gg = l >> 4;
    int il = 96 + gg * 4 + j;
    float v = 0.f;
    if (il < DD && jout < DD) v = wblockdiag(jout, g * DD + il, HMw, MEw, TFw);
    else if (il == DD && g == 0 && jout < DD) {
      if (jout < 80)       v = HMb[jout];
      else if (jout < 100) v = MEb[jout - 80];
      else                 v = TFb[jout - 100];
    }
    Wfrag[g * SLAB + HOFF + jt * 256 + l * 4 + j] = f2bf(v);
  }
  for (int a = tid; a < NATT * 256; a += NT)
    Wfrag[(a >> 8) * SLAB + 12544 + (a & 255)] = 0;

  for (int a = tid; a < NATT * KP; a += NT) {
    int g = a / KP, n = a - g * KP;
    int i = g * DD + n;
    int col;
    if (i < 800)       col = i % 80;
    else if (i < 1000) col = 80 + (i - 800) % 20;
    else if (i < 1050) col = 100 + (i - 1000) % 5;
    else               col = 100;  // alpha==0 there
    Lut8[a] = (unsigned char)col;
  }
}

// ---------------- main fused kernel ----------------
// 1024 blocks x 512 threads; 8 waves x 16 rows; 2 __syncthreads per group.
// LDS: ctx 28672 + A 25600 + W 25600 + lut 1120 = 80992B -> 2 blocks/CU,
// 16 waves/CU at 128-VGPR cap.
__global__ __launch_bounds__(512, 4)
void fused_main(const float* __restrict__ hm, const float* __restrict__ me,
                const float* __restrict__ tf,
                const short* __restrict__ Afrag, const short* __restrict__ Wfrag,
                const unsigned char* __restrict__ Lut8,
                float* __restrict__ out, float* __restrict__ alphaOut)
{
  __shared__ __align__(16) short sCtx[RPB * KP];        // 28672 B
  __shared__ __align__(16) short sAb[SLAB];             // 25600 B
  __shared__ __align__(16) short sWb[SLAB];             // 25600 B
  __shared__ __align__(4)  unsigned char sLut8[NATT * KP]; // 1120 B

  const int tid  = threadIdx.x;
  const int lane = tid & 63;
  const int wave = tid >> 6;          // 0..7
  const int l15  = lane & 15;
  const int g16  = lane >> 4;
  const long rowbase = (long)blockIdx.x * RPB;
  const int wrow0 = wave * 16;

  // ---- issue A(0), W(0) staging (25 chunks each, over 8 waves) ----
  #pragma unroll
  for (int q = 0; q < 4; ++q) {
    int ch = q * 8 + wave;
    if (ch < 25) {
      gload_lds16(Afrag + ch * 512 + lane * 8, sAb + ch * 512 + lane * 8);
      gload_lds16(Wfrag + ch * 512 + lane * 8, sWb + ch * 512 + lane * 8);
    }
  }

  // ---- wave-private ctx staging (rows wrow0..wrow0+15), KP=112 ----
  for (int q = lane; q < 16 * 20; q += 64) {        // hm: 20 f4 per row
    int r = q / 20, c = q - r * 20;
    f4 v = *(const f4*)(hm + (rowbase + wrow0 + r) * 80 + c * 4);
    u32x2 b; b[0] = pkbf(v[0], v[1]); b[1] = pkbf(v[2], v[3]);
    *(u32x2*)&sCtx[(wrow0 + r) * KP + c * 4] = b;
  }
  for (int q = lane; q < 16 * 5; q += 64) {         // me: 5 f4 per row
    int r = q / 5, c = q - r * 5;
    f4 v = *(const f4*)(me + (rowbase + wrow0 + r) * 20 + c * 4);
    u32x2 b; b[0] = pkbf(v[0], v[1]); b[1] = pkbf(v[2], v[3]);
    *(u32x2*)&sCtx[(wrow0 + r) * KP + 80 + c * 4] = b;
  }
  for (int q = lane; q < 16 * 5; q += 64) {         // tf: 5 scalars per row
    int r = q / 5, c = q - r * 5;
    sCtx[(wrow0 + r) * KP + 100 + c] = f2bf(tf[(rowbase + wrow0 + r) * 5 + c]);
  }
  for (int q = lane; q < 16 * 7; q += 64) {         // cols 105..111; col105 = 1.0
    int r = q / 7, c = q - r * 7;
    sCtx[(wrow0 + r) * KP + 105 + c] = (c == 0) ? (short)0x3F80 : (short)0;
  }
  for (int q = tid; q < (NATT * KP) / 4; q += 512)  // u8 LUT
    ((unsigned int*)sLut8)[q] = ((const unsigned int*)Lut8)[q];

  // ---- preload ctx MFMA fragments (group-invariant, wave-private rows) ----
  short8v cf[3];
  #pragma unroll
  for (int c = 0; c < 3; ++c)
    cf[c] = *(const short8v*)&sCtx[(wrow0 + l15) * KP + c * 32 + g16 * 8];
  short8v cf3x;
  {
    short4v c4 = *(const short4v*)&sCtx[(wrow0 + l15) * KP + 96 + g16 * 4];
    cf3x = short8v{c4[0], c4[1], c4[2], c4[3], 0, 0, 0, 0};
  }

  f4 acc2[7];
  #pragma unroll
  for (int jt = 0; jt < 7; ++jt) {
    acc2[jt][0]=0.f; acc2[jt][1]=0.f; acc2[jt][2]=0.f; acc2[jt][3]=0.f;
  }

  __syncthreads();   // prologue: A(0),W(0) landed + ctx/LUT visible

  for (int g = 0; g < NATT; ++g) {
    // ---- GEMM1: z tile D[n][r], n=16T+4*g16+reg, r=l15; K=112 ----
    f4 za[7];
    #pragma unroll
    for (int T = 0; T < 7; ++T) { za[T][0]=0.f; za[T][1]=0.f; za[T][2]=0.f; za[T][3]=0.f; }

    #pragma unroll
    for (int c = 0; c < 3; ++c) {
      #pragma unroll
      for (int T = 0; T < 7; ++T) {
        short8v af = *(const short8v*)&sAb[(c * 7 + T) * FRAG_ELEMS + lane * 8];
        za[T] = __builtin_amdgcn_mfma_f32_16x16x32_bf16(af, cf[c], za[T], 0, 0, 0);
      }
    }
    #pragma unroll
    for (int T = 0; T < 7; ++T) {                     // half chunk k=96..111
      short4v a4 = *(const short4v*)&sAb[HOFF + T * 256 + lane * 4];
      short8v af3 = short8v{a4[0], a4[1], a4[2], a4[3], 0, 0, 0, 0};
      za[T] = __builtin_amdgcn_mfma_f32_16x16x32_bf16(af3, cf3x, za[T], 0, 0, 0);
    }

    __syncthreads();   // B1: sAb(g) reads done block-wide

    // ---- stage A(g+1) (covered by softmax+GEMM2; drained at B2) ----
    if (g < NATT - 1) {
      const short* src = Afrag + (g + 1) * SLAB;
      #pragma unroll
      for (int q = 0; q < 4; ++q) {
        int ch = q * 8 + wave;
        if (ch < 25) gload_lds16(src + ch * 512 + lane * 8, sAb + ch * 512 + lane * 8);
      }
    }

    // ---- LUT quads ----
    unsigned int cq[7];
    #pragma unroll
    for (int T = 0; T < 7; ++T)
      cq[T] = *(const unsigned int*)&sLut8[g * KP + T * 16 + g16 * 4];

    // ---- softmax (exp2 of prescaled z, no max-subtract) ----
    float s = 0.f;
    #pragma unroll
    for (int T = 0; T < 7; ++T)
      #pragma unroll
      for (int k = 0; k < 4; ++k) {
        float p = exp2f(za[T][k]);
        za[T][k] = p;
        s += p;
      }
    s += __shfl_xor(s, 16);
    s += __shfl_xor(s, 32);
    float inv = __fdividef(1.f, s);

    const int rowl = wrow0 + l15;
    float* arow = alphaOut + (rowbase + rowl) * 1050 + g * DD;
    const short* crow = &sCtx[rowl * KP];

    // ---- alpha store + h build ----
    u32x4 hfu[4];
    #pragma unroll
    for (int T = 0; T < 7; ++T) {
      f4 av = za[T] * inv;
      int n0 = T * 16 + g16 * 4;
      if (T < 6) {
        *(f4u*)(arow + n0) = av;               // dwordx4
      } else {
        if (g16 < 2)       *(f4u*)(arow + n0) = av;
        else if (g16 == 2) arow[104] = av[0];  // n=104 only; n>=105 masked
      }
      float h0 = av[0] * bf2f(crow[(cq[T] >>  0) & 0xFF]);
      float h1 = av[1] * bf2f(crow[(cq[T] >>  8) & 0xFF]);
      float h2 = av[2] * bf2f(crow[(cq[T] >> 16) & 0xFF]);
      float h3 = av[3] * bf2f(crow[(cq[T] >> 24) & 0xFF]);
      hfu[T >> 1][(T & 1) * 2 + 0] = pkbf(h0, h1);
      hfu[T >> 1][(T & 1) * 2 + 1] = pkbf(h2, h3);
    }
    hfu[3][2] = 0u; hfu[3][3] = 0u;                 // half-chunk upper slots = 0
    if (g == 0 && g16 == 2) {                       // il=105 slot := 1.0 (out-bias)
      hfu[3][0] = (hfu[3][0] & 0xFFFFu) | 0x3F800000u;
    }

    // ---- GEMM2 from LDS: jt-outer; 3 full + 1 half chunk per jt ----
    short8v ha0 = __builtin_bit_cast(short8v, hfu[0]);
    short8v ha1 = __builtin_bit_cast(short8v, hfu[1]);
    short8v ha2 = __builtin_bit_cast(short8v, hfu[2]);
    short8v ha3 = __builtin_bit_cast(short8v, hfu[3]);
    #pragma unroll
    for (int jt = 0; jt < 7; ++jt) {
      short8v w0 = *(const short8v*)&sWb[(0 * 7 + jt) * FRAG_ELEMS + lane * 8];
      short8v w1 = *(const short8v*)&sWb[(1 * 7 + jt) * FRAG_ELEMS + lane * 8];
      short8v w2 = *(const short8v*)&sWb[(2 * 7 + jt) * FRAG_ELEMS + lane * 8];
      short4v w3h = *(const short4v*)&sWb[HOFF + jt * 256 + lane * 4];
      short8v w3 = short8v{w3h[0], w3h[1], w3h[2], w3h[3], 0, 0, 0, 0};
      f4 a = acc2[jt];
      a = __builtin_amdgcn_mfma_f32_16x16x32_bf16(ha0, w0, a, 0, 0, 0);
      a = __builtin_amdgcn_mfma_f32_16x16x32_bf16(ha1, w1, a, 0, 0, 0);
      a = __builtin_amdgcn_mfma_f32_16x16x32_bf16(ha2, w2, a, 0, 0, 0);
      a = __builtin_amdgcn_mfma_f32_16x16x32_bf16(ha3, w3, a, 0, 0, 0);
      acc2[jt] = a;
    }

    __syncthreads();   // B2: sWb(g) reads done; drain -> A(g+1) landed

    // ---- stage W(g+1) (covered by next GEMM1; drained at B1 of next iter) ----
    if (g < NATT - 1) {
      const short* src = Wfrag + (g + 1) * SLAB;
      #pragma unroll
      for (int q = 0; q < 4; ++q) {
        int ch = q * 8 + wave;
        if (ch < 25) gload_lds16(src + ch * 512 + lane * 8, sWb + ch * 512 + lane * 8);
      }
    }
  }

  // ---- epilogue: bias already in acc2; D2[r][j]: r=4*g16+k, j=16*jt+l15 ----
  #pragma unroll
  for (int jt = 0; jt < 7; ++jt) {
    int j = jt * 16 + l15;
    if (j < DD) {
      #pragma unroll
      for (int k = 0; k < 4; ++k) {
        long row = rowbase + wrow0 + g16 * 4 + k;
        out[row * DD + j] = acc2[jt][k];
      }
    }
  }
}

// ---------------- launch ----------------
extern "C" void kernel_launch(void* const* d_in, const int* in_sizes, int n_in,
                              void* d_out, int out_size, void* d_ws, size_t ws_size,
                              hipStream_t stream)
{
  const float* hm  = (const float*)d_in[0];
  const float* me  = (const float*)d_in[1];
  const float* tf  = (const float*)d_in[2];
  const float* Aw  = (const float*)d_in[3];
  const float* Ab  = (const float*)d_in[4];
  const float* HMw = (const float*)d_in[5];
  const float* HMb = (const float*)d_in[6];
  const float* MEw = (const float*)d_in[7];
  const float* MEb = (const float*)d_in[8];
  const float* TFw = (const float*)d_in[9];
  const float* TFb = (const float*)d_in[10];

  char* ws = (char*)d_ws;
  short* Afrag = (short*)(ws + 0);                 // 256000 B
  short* Wfrag = (short*)(ws + 256000);            // 256000 B
  unsigned char* Lut8 = (unsigned char*)(ws + 512000); // 1120 B (total 513120)

  float* outP     = (float*)d_out;
  float* alphaOut = outP + (long)131072 * DD;

  prep_kernel<<<320, 256, 0, stream>>>(Aw, Ab, HMw, HMb, MEw, MEb, TFw, TFb,
                                       Afrag, Wfrag, Lut8);
  fused_main<<<1024, 512, 0, stream>>>(hm, me, tf, Afrag, Wfrag, Lut8,
                                       outP, alphaOut);
}